// Round 8
// baseline (190.366 us; speedup 1.0000x reference)
//
#include <hip/hip_runtime.h>
#include <math.h>

constexpr int B_  = 64;
constexpr int LQ_ = 64;
constexpr int LS_ = 512;
constexpr int S_  = 512;
#define NEGV (-1e6f)
#define MARGIN 0.0625f

typedef __attribute__((ext_vector_type(8))) short bf16x8;
typedef __attribute__((ext_vector_type(4))) float f32x4;

__device__ inline unsigned short f2bf_rn(float x) {
    unsigned u = __builtin_bit_cast(unsigned, x);
    unsigned r = (u + 0x7FFFu + ((u >> 16) & 1u)) >> 16;
    return (unsigned short)r;
}

// ---------------- Kernel A: support f32 -> staged bf16 ----------------
// Aprep shorts layout: ((b*2+rc)*16 + i)*8192 + kc*2048 + row'*8 + e
// where global row = rc*256+row', k = i*32 + kc*8 + e.
__global__ __launch_bounds__(512)
void prep_support_kernel(const float* __restrict__ support, short* __restrict__ Aprep)
{
    int bid = blockIdx.x;              // 512 blocks: b*8 + rg
    int b = bid >> 3, rg = bid & 7;
    int t = threadIdx.x;
    int r  = t & 63;                   // row within 64-row group
    int cg = t >> 6;                   // d-chunk group 0..7 (64 d each)
    int row  = rg * 64 + r;
    int rc   = row >> 8;
    int rowp = row & 255;
    const float* src = support + ((size_t)(b * LS_ + row)) * S_;

    #pragma unroll
    for (int ii = 0; ii < 2; ++ii) {
        int i = cg * 2 + ii;
        #pragma unroll
        for (int kc = 0; kc < 4; ++kc) {
            int d0 = i * 32 + kc * 8;
            float4 f0 = *(const float4*)(src + d0);
            float4 f1 = *(const float4*)(src + d0 + 4);
            uint4 H;
            H.x = f2bf_rn(f0.x) | ((unsigned)f2bf_rn(f0.y) << 16);
            H.y = f2bf_rn(f0.z) | ((unsigned)f2bf_rn(f0.w) << 16);
            H.z = f2bf_rn(f1.x) | ((unsigned)f2bf_rn(f1.y) << 16);
            H.w = f2bf_rn(f1.z) | ((unsigned)f2bf_rn(f1.w) << 16);
            size_t off = ((size_t)(b * 2 + rc) * 16 + i) * 8192 + kc * 2048 + rowp * 8;
            *(uint4*)&Aprep[off] = H;
        }
    }
}

// ---------------- Kernel 1: question attention pooling ----------------
__global__ __launch_bounds__(256)
void qpool_kernel(const float* __restrict__ eq, const int* __restrict__ qlen,
                  const float* __restrict__ W_qa, float* __restrict__ q_state)
{
    int b = blockIdx.x;
    int t = threadIdx.x;
    int wave = t >> 6, lane = t & 63;
    __shared__ float att[LQ_];
    __shared__ float wsm[LQ_];
    const float* eqb = eq + (size_t)b * LQ_ * S_;

    for (int k = 0; k < 16; ++k) {
        int q = wave + 4 * k;
        const float* row = eqb + q * S_;
        float s = 0.f;
        #pragma unroll
        for (int j = 0; j < S_ / 64; ++j)
            s = fmaf(row[lane + 64 * j], W_qa[lane + 64 * j], s);
        #pragma unroll
        for (int off = 32; off >= 1; off >>= 1)
            s += __shfl_xor(s, off);
        if (lane == 0) att[q] = s;
    }
    __syncthreads();

    if (wave == 0) {
        int L = qlen[b];
        float v = att[lane] + ((lane < L) ? 0.f : NEGV);
        float m = v;
        #pragma unroll
        for (int off = 32; off >= 1; off >>= 1)
            m = fmaxf(m, __shfl_xor(m, off));
        float e = expf(v - m);
        float sum = e;
        #pragma unroll
        for (int off = 32; off >= 1; off >>= 1)
            sum += __shfl_xor(sum, off);
        wsm[lane] = e / sum;
    }
    __syncthreads();

    for (int d = t; d < S_; d += 256) {
        float acc = 0.f;
        #pragma unroll 8
        for (int q = 0; q < LQ_; ++q)
            acc = fmaf(wsm[q], eqb[q * S_ + d], acc);
        q_state[b * S_ + d] = acc;
    }
}

// ---------------- Kernel 2: q_start_inter / q_end_inter (f32 exact) --------
__global__ __launch_bounds__(512)
void inter_kernel(const float* __restrict__ q_state,
                  const float* __restrict__ W_qsi, const float* __restrict__ b_qsi,
                  const float* __restrict__ W_qei, const float* __restrict__ b_qei,
                  float* __restrict__ qsi, float* __restrict__ qei)
{
    int b = blockIdx.x;
    const float* W  = blockIdx.y ? W_qei : W_qsi;
    const float* bi = blockIdx.y ? b_qei : b_qsi;
    float*       o  = blockIdx.y ? qei   : qsi;
    int t = threadIdx.x, lane = t & 63, w = t >> 6;
    __shared__ float qs[S_];
    __shared__ float red[8][S_];
    qs[t] = q_state[b * S_ + t];
    __syncthreads();

    float z[8];
    #pragma unroll
    for (int k = 0; k < 8; ++k) z[k] = 0.f;
    const int d0 = w * 64;
    #pragma unroll 4
    for (int dd = 0; dd < 64; ++dd) {
        int d = d0 + dd;
        float q = qs[d];
        const float* row = W + (size_t)d * S_ + lane;
        #pragma unroll
        for (int k = 0; k < 8; ++k)
            z[k] = fmaf(q, row[k * 64], z[k]);
    }
    #pragma unroll
    for (int k = 0; k < 8; ++k) red[w][k * 64 + lane] = z[k];
    __syncthreads();
    float acc = bi[t];
    #pragma unroll
    for (int ww = 0; ww < 8; ++ww) acc += red[ww][t];
    o[b * S_ + t] = acc;
}

// ---------------- Kernel P: per-batch folded weight prep (bf16, staged) ----
// Wc shorts layout: ((b*2+cc)*16 + i)*8192 + kc*2048 + col'*8 + e
// global col = cc*256+col', k = i*32+kc*8+e.
template <int NT>
__global__ __launch_bounds__(512)
void prep_kernel(const float* __restrict__ W, const float* __restrict__ q_state,
                 const float* __restrict__ u_s, short* __restrict__ Wc)
{
    int bid = blockIdx.x;
    int i = bid >> 6, b = bid & 63;     // 64 consecutive blocks share W slice (L2)
    int col = threadIdx.x;
    int cc = col >> 8, colp = col & 255;
    __shared__ float scq[32], scu[32];
    if (col < 32) scq[col] = q_state[b * S_ + i * 32 + col];
    if (NT == 3 && col >= 32 && col < 64) scu[col - 32] = u_s[b * S_ + i * 32 + col - 32];
    __syncthreads();

    unsigned short h[32];
    #pragma unroll
    for (int d = 0; d < 32; ++d) {
        int D = i * 32 + d;
        float v;
        if (NT == 2)
            v = fmaf(scq[d], W[(size_t)D * S_ + col], W[(size_t)(S_ + D) * S_ + col]);
        else
            v = fmaf(scu[d], W[(size_t)D * S_ + col],
                fmaf(scq[d], W[(size_t)(S_ + D) * S_ + col], W[(size_t)(2 * S_ + D) * S_ + col]));
        h[d] = f2bf_rn(v);
    }
    size_t base = ((size_t)(b * 2 + cc) * 16 + i) * 8192 + (size_t)colp * 8;
    #pragma unroll
    for (int kc = 0; kc < 4; ++kc) {
        uint4 H;
        H.x = h[kc*8+0] | ((unsigned)h[kc*8+1] << 16);
        H.y = h[kc*8+2] | ((unsigned)h[kc*8+3] << 16);
        H.z = h[kc*8+4] | ((unsigned)h[kc*8+5] << 16);
        H.w = h[kc*8+6] | ((unsigned)h[kc*8+7] << 16);
        *(uint4*)&Wc[base + kc * 2048] = H;
    }
}

// ---------------- Kernel S: 256x256-tile 1-term bf16 MFMA score ------------
// Writes RAW partial row-sums (no masks) to out[cc][b][l].
__global__ __launch_bounds__(512, 2)
void score_kernel(const short* __restrict__ Aprep, const short* __restrict__ Wc,
                  const float* __restrict__ inter, const float* __restrict__ Wsmall,
                  float* __restrict__ out)
{
    const int t = threadIdx.x;
    const int lane = t & 63, wid = t >> 6;
    const int wr = wid >> 2, wc = wid & 3;
    const int l15 = lane & 15, l4 = lane >> 4;

    // XCD-grouped: the 4 blocks of a batch (2rc x 2cc) land on one XCD
    int lid = blockIdx.x;
    int xcd = lid & 7, slot = lid >> 3;        // slot 0..31
    int b  = xcd * 8 + (slot >> 2);
    int rc = (slot >> 1) & 1;
    int cc = slot & 1;

    __shared__ __attribute__((aligned(16))) short As[2][8192];  // 32 KB
    __shared__ __attribute__((aligned(16))) short Bs[2][8192];  // 32 KB
    __shared__ float int_l[256], wsm_l[256];
    __shared__ float sm_red[256][4];

    if (t < 256) {
        int_l[t] = inter[b * S_ + cc * 256 + t];
        wsm_l[t] = Wsmall[cc * 256 + t];
    }

    const char* Abase = (const char*)(Aprep + ((size_t)(b * 2 + rc) * 16) * 8192);
    const char* Bbase = (const char*)(Wc    + ((size_t)(b * 2 + cc) * 16) * 8192);

    f32x4 acc[8][4];
    #pragma unroll
    for (int r = 0; r < 8; ++r)
        #pragma unroll
        for (int c = 0; c < 4; ++c)
            acc[r][c] = (f32x4){0.f, 0.f, 0.f, 0.f};

    auto stage = [&](int i, int buf) {
        const char* ga = Abase + (size_t)i * 16384 + t * 16;
        const char* gb = Bbase + (size_t)i * 16384 + t * 16;
        char* la = (char*)As[buf] + t * 16;
        char* lb = (char*)Bs[buf] + t * 16;
        __builtin_amdgcn_global_load_lds(
            (const __attribute__((address_space(1))) void*)ga,
            (__attribute__((address_space(3))) void*)la, 16, 0, 0);
        __builtin_amdgcn_global_load_lds(
            (const __attribute__((address_space(1))) void*)(ga + 8192),
            (__attribute__((address_space(3))) void*)(la + 8192), 16, 0, 0);
        __builtin_amdgcn_global_load_lds(
            (const __attribute__((address_space(1))) void*)gb,
            (__attribute__((address_space(3))) void*)lb, 16, 0, 0);
        __builtin_amdgcn_global_load_lds(
            (const __attribute__((address_space(1))) void*)(gb + 8192),
            (__attribute__((address_space(3))) void*)(lb + 8192), 16, 0, 0);
    };

    stage(0, 0);

    for (int i = 0; i < 16; ++i) {
        const int buf = i & 1;
        if (i + 1 < 16) {
            stage(i + 1, buf ^ 1);
            asm volatile("s_waitcnt vmcnt(4)" ::: "memory");
        } else {
            asm volatile("s_waitcnt vmcnt(0)" ::: "memory");
        }
        __builtin_amdgcn_s_barrier();

        bf16x8 ah[8];
        #pragma unroll
        for (int r = 0; r < 8; ++r) {
            int rowp = wr * 128 + r * 16 + l15;
            ah[r] = *(const bf16x8*)&As[buf][l4 * 2048 + rowp * 8];
        }
        #pragma unroll
        for (int c = 0; c < 4; ++c) {
            int colp = wc * 64 + c * 16 + l15;
            bf16x8 bh = *(const bf16x8*)&Bs[buf][l4 * 2048 + colp * 8];
            #pragma unroll
            for (int r = 0; r < 8; ++r)
                acc[r][c] = __builtin_amdgcn_mfma_f32_16x16x32_bf16(ah[r], bh, acc[r][c], 0, 0, 0);
        }
        asm volatile("s_waitcnt lgkmcnt(0)" ::: "memory");
        __builtin_amdgcn_s_barrier();
    }

    // epilogue: + inter, relu, dot Wsmall, row-reduce over the wave's 64 cols
    #pragma unroll
    for (int r = 0; r < 8; ++r) {
        #pragma unroll
        for (int jj = 0; jj < 4; ++jj) {
            float pr = 0.f;
            #pragma unroll
            for (int c = 0; c < 4; ++c) {
                int colp = wc * 64 + c * 16 + l15;
                float v = acc[r][c][jj] + int_l[colp];
                v = fmaxf(v, 0.f);
                pr = fmaf(v, wsm_l[colp], pr);
            }
            pr += __shfl_xor(pr, 1);
            pr += __shfl_xor(pr, 2);
            pr += __shfl_xor(pr, 4);
            pr += __shfl_xor(pr, 8);
            if (l15 == 0) sm_red[wr * 128 + r * 16 + l4 * 4 + jj][wc] = pr;
        }
    }
    __syncthreads();
    if (t < 256) {
        int l = rc * 256 + t;
        float s = sm_red[t][0] + sm_red[t][1] + sm_red[t][2] + sm_red[t][3];
        out[((size_t)cc * B_ * LS_) + b * LS_ + l] = s;   // raw partial, no masks
    }
}

// ---------------- combine: sum cc-halves, apply masks ONCE ----------------
__global__ __launch_bounds__(256)
void combine_kernel(const float* __restrict__ part0, const float* __restrict__ part1,
                    const int* __restrict__ slen, const int* __restrict__ sp,
                    int endflag, float* __restrict__ out)
{
    int g = blockIdx.x * 256 + threadIdx.x;
    int b = g >> 9, l = g & 511;
    float s = part0[g] + part1[g];
    if (l >= slen[b]) s += NEGV;
    if (endflag && l < sp[b]) s += NEGV;
    out[g] = s;
}

// ---------------- candidate selection (shared by rescue/finalize) ----------
__device__ inline int select_cands(const float* s_l, int t, int lane, int w,
                                   float* wred, int* wcnt, int* cand)
{
    float v = s_l[t];
    #pragma unroll
    for (int off = 32; off >= 1; off >>= 1)
        v = fmaxf(v, __shfl_xor(v, off));
    if (lane == 0) wred[w] = v;
    __syncthreads();
    float m = wred[0];
    #pragma unroll
    for (int k = 1; k < 8; ++k) m = fmaxf(m, wred[k]);
    float th = m - MARGIN;
    bool flag = s_l[t] >= th;
    unsigned long long bal = __ballot(flag);
    int rank = __popcll(bal & ((1ull << lane) - 1ull));
    if (lane == 0) wcnt[w] = (int)__popcll(bal);
    __syncthreads();
    int off = 0, total = 0;
    #pragma unroll
    for (int k = 0; k < 8; ++k) { if (k < w) off += wcnt[k]; total += wcnt[k]; }
    if (flag) { int pos = off + rank; if (pos < 8) cand[pos] = t; }
    __syncthreads();
    return total < 8 ? total : 8;
}

// ---------------- Kernel R: exact f32 rescue, wave-parallel over d ----------
template <bool END>
__global__ __launch_bounds__(512)
void rescue_kernel(const float* __restrict__ support, const float* __restrict__ q_state,
                   const float* __restrict__ u_s, const float* __restrict__ Wbig,
                   const float* __restrict__ inter, const float* __restrict__ Wsmall,
                   const float* __restrict__ scores, float* __restrict__ part)
{
    int bid = blockIdx.x;
    int b = bid >> 2, chunk = bid & 3;
    int t = threadIdx.x, lane = t & 63, w = t >> 6;
    __shared__ float s_l[S_], qs_l[S_], us_l[S_];
    __shared__ float arow[8][S_];
    __shared__ float red[8][8][128];
    __shared__ float wred[8];
    __shared__ int wcnt[8], cand[8];

    s_l[t]  = scores[b * S_ + t];
    qs_l[t] = q_state[b * S_ + t];
    if (END) us_l[t] = u_s[b * S_ + t];
    #pragma unroll
    for (int c = 0; c < 8; ++c) arow[c][t] = 0.f;
    __syncthreads();

    int cnt = select_cands(s_l, t, lane, w, wred, wcnt, cand);

    for (int c = 0; c < cnt; ++c)
        arow[c][t] = support[((size_t)(b * LS_ + cand[c])) * S_ + t];
    __syncthreads();

    float z0[8], z1[8];
    #pragma unroll
    for (int c = 0; c < 8; ++c) { z0[c] = 0.f; z1[c] = 0.f; }

    const int d0 = w * 64;
    const int s0 = chunk * 128 + lane, s1 = s0 + 64;
    const float* W1 = Wbig;
    const float* W2 = Wbig + (size_t)S_ * S_;
    const float* W3 = Wbig + (size_t)2 * S_ * S_;

    #pragma unroll 4
    for (int dd = 0; dd < 64; ++dd) {
        int d = d0 + dd;
        float r1a = W1[(size_t)d * S_ + s0], r1b = W1[(size_t)d * S_ + s1];
        float r2a = W2[(size_t)d * S_ + s0], r2b = W2[(size_t)d * S_ + s1];
        float r3a = 0.f, r3b = 0.f;
        if (END) { r3a = W3[(size_t)d * S_ + s0]; r3b = W3[(size_t)d * S_ + s1]; }
        float q = qs_l[d];
        float u = END ? us_l[d] : 0.f;
        #pragma unroll
        for (int c = 0; c < 8; ++c) {
            float a = arow[c][d];
            if (END) {
                float ua = u * a, qa = q * a;
                z0[c] = fmaf(ua, r1a, fmaf(qa, r2a, fmaf(a, r3a, z0[c])));
                z1[c] = fmaf(ua, r1b, fmaf(qa, r2b, fmaf(a, r3b, z1[c])));
            } else {
                float qa = q * a;
                z0[c] = fmaf(qa, r1a, fmaf(a, r2a, z0[c]));
                z1[c] = fmaf(qa, r1b, fmaf(a, r2b, z1[c]));
            }
        }
    }
    #pragma unroll
    for (int c = 0; c < 8; ++c) {
        red[w][c][lane]      = z0[c];
        red[w][c][64 + lane] = z1[c];
    }
    __syncthreads();

    {
        float a0 = 0.f, a1 = 0.f;
        #pragma unroll
        for (int ww = 0; ww < 8; ++ww) {
            a0 += red[ww][w][lane];
            a1 += red[ww][w][64 + lane];
        }
        float v0 = fmaxf(a0 + inter[b * S_ + s0], 0.f) * Wsmall[s0];
        float v1 = fmaxf(a1 + inter[b * S_ + s1], 0.f) * Wsmall[s1];
        float p = v0 + v1;
        #pragma unroll
        for (int off = 32; off >= 1; off >>= 1)
            p += __shfl_xor(p, off);
        if (lane == 0 && w < cnt) part[((size_t)b * 8 + w) * 4 + chunk] = p;
    }
}

// ---------------- Kernel F: finalize (exact argmax, sp/u_s/pred) ----------
template <bool END>
__global__ __launch_bounds__(512)
void finalize_kernel(const float* __restrict__ scores, const float* __restrict__ part,
                     const float* __restrict__ support, int* __restrict__ sp_ws,
                     float* __restrict__ pred, float* __restrict__ us_out)
{
    int b = blockIdx.x;
    int t = threadIdx.x, lane = t & 63, w = t >> 6;
    __shared__ float s_l[S_];
    __shared__ float wred[8];
    __shared__ int wcnt[8], cand[8];
    __shared__ int best_sh;

    s_l[t] = scores[b * S_ + t];
    __syncthreads();
    int cnt = select_cands(s_l, t, lane, w, wred, wcnt, cand);

    if (t == 0) {
        float bv = -INFINITY;
        int bi = cand[0];
        for (int c = 0; c < cnt; ++c) {
            const float* pp = part + ((size_t)b * 8 + c) * 4;
            float e = ((pp[0] + pp[1]) + pp[2]) + pp[3];
            if (e > bv) { bv = e; bi = cand[c]; }
        }
        best_sh = bi;
        pred[b] = (float)bi;
        if (!END) sp_ws[b] = bi;
    }
    __syncthreads();
    if (!END)
        us_out[b * S_ + t] = support[((size_t)(b * LS_ + best_sh)) * S_ + t];
}

// ---------------- launch ----------------
extern "C" void kernel_launch(void* const* d_in, const int* in_sizes, int n_in,
                              void* d_out, int out_size, void* d_ws, size_t ws_size,
                              hipStream_t stream)
{
    const float* eq    = (const float*)d_in[0];
    const float* es    = (const float*)d_in[1];
    const int*   qlen  = (const int*)d_in[2];
    const int*   slen  = (const int*)d_in[3];
    const float* W_qa  = (const float*)d_in[7];
    const float* W_qsi = (const float*)d_in[8];
    const float* b_qsi = (const float*)d_in[9];
    const float* W_qs  = (const float*)d_in[10];
    const float* W_ss  = (const float*)d_in[11];
    const float* W_qei = (const float*)d_in[12];
    const float* b_qei = (const float*)d_in[13];
    const float* W_qe  = (const float*)d_in[14];
    const float* W_es  = (const float*)d_in[15];

    float* out          = (float*)d_out;
    float* start_scores = out;
    float* end_scores   = out + B_ * LS_;
    float* pred_start   = out + 2 * B_ * LS_;
    float* pred_end     = out + 2 * B_ * LS_ + B_;

    float* ws      = (float*)d_ws;
    float* q_state = ws;                       // [B,S]
    float* qsi     = ws + B_ * S_;             // [B,S]
    float* qei     = ws + 2 * B_ * S_;         // [B,S]
    float* u_s     = ws + 3 * B_ * S_;         // [B,S]
    float* part    = ws + 4 * B_ * S_;         // [B,8,4]
    int*   sp_ws   = (int*)(ws + 4 * B_ * S_ + 2048);   // [B]
    float* scpart  = ws + 4 * B_ * S_ + 4096;  // [2, B, LS] cc-partials (256 KB)
    short* Wc      = (short*)(scpart + 2 * B_ * LS_);   // 33.5 MB
    short* Aprep   = Wc + (size_t)B_ * 2 * 16 * 8192;   // 33.5 MB

    prep_support_kernel<<<512, 512, 0, stream>>>(es, Aprep);
    qpool_kernel<<<B_, 256, 0, stream>>>(eq, qlen, W_qa, q_state);
    inter_kernel<<<dim3(B_, 2), 512, 0, stream>>>(q_state, W_qsi, b_qsi, W_qei, b_qei, qsi, qei);

    // ---- start pass ----
    prep_kernel<2><<<1024, 512, 0, stream>>>(W_qs, q_state, nullptr, Wc);
    score_kernel<<<256, 512, 0, stream>>>(Aprep, Wc, qsi, W_ss, scpart);
    combine_kernel<<<B_ * LS_ / 256, 256, 0, stream>>>(scpart, scpart + B_ * LS_,
                                                       slen, sp_ws, 0, start_scores);
    rescue_kernel<false><<<256, 512, 0, stream>>>(es, q_state, nullptr, W_qs, qsi, W_ss,
                                                  start_scores, part);
    finalize_kernel<false><<<B_, 512, 0, stream>>>(start_scores, part, es, sp_ws, pred_start, u_s);

    // ---- end pass ----
    prep_kernel<3><<<1024, 512, 0, stream>>>(W_qe, q_state, u_s, Wc);
    score_kernel<<<256, 512, 0, stream>>>(Aprep, Wc, qei, W_es, scpart);
    combine_kernel<<<B_ * LS_ / 256, 256, 0, stream>>>(scpart, scpart + B_ * LS_,
                                                       slen, sp_ws, 1, end_scores);
    rescue_kernel<true><<<256, 512, 0, stream>>>(es, q_state, u_s, W_qe, qei, W_es,
                                                 end_scores, part);
    finalize_kernel<true><<<B_, 512, 0, stream>>>(end_scores, part, es, nullptr, pred_end, nullptr);
}

// Round 9
// 187.419 us; speedup vs baseline: 1.0157x; 1.0157x over previous
//
#include <hip/hip_runtime.h>
#include <math.h>

constexpr int B_  = 64;
constexpr int LQ_ = 64;
constexpr int LS_ = 512;
constexpr int S_  = 512;
#define NEGV (-1e6f)
#define MARGIN 0.0625f

typedef __attribute__((ext_vector_type(8))) short bf16x8;
typedef __attribute__((ext_vector_type(4))) float f32x4;

__device__ inline unsigned short f2bf_rn(float x) {
    unsigned u = __builtin_bit_cast(unsigned, x);
    unsigned r = (u + 0x7FFFu + ((u >> 16) & 1u)) >> 16;
    return (unsigned short)r;
}

// ---------------- Kernel A: support f32 -> staged bf16 ----------------
// Aprep shorts: ((b*2+rc2)*16 + i)*8192 + kc*2048 + rowp*8 + e
// rc2 = row>>8, rowp = row&255; k = i*32 + kc*8 + e.
__global__ __launch_bounds__(512)
void prep_support_kernel(const float* __restrict__ support, short* __restrict__ Aprep)
{
    int bid = blockIdx.x;              // 512 blocks: b*8 + rg
    int b = bid >> 3, rg = bid & 7;
    int t = threadIdx.x;
    int r  = t & 63;
    int cg = t >> 6;
    int row  = rg * 64 + r;
    int rc2  = row >> 8;
    int rowp = row & 255;
    const float* src = support + ((size_t)(b * LS_ + row)) * S_;

    #pragma unroll
    for (int ii = 0; ii < 2; ++ii) {
        int i = cg * 2 + ii;
        #pragma unroll
        for (int kc = 0; kc < 4; ++kc) {
            int d0 = i * 32 + kc * 8;
            float4 f0 = *(const float4*)(src + d0);
            float4 f1 = *(const float4*)(src + d0 + 4);
            uint4 H;
            H.x = f2bf_rn(f0.x) | ((unsigned)f2bf_rn(f0.y) << 16);
            H.y = f2bf_rn(f0.z) | ((unsigned)f2bf_rn(f0.w) << 16);
            H.z = f2bf_rn(f1.x) | ((unsigned)f2bf_rn(f1.y) << 16);
            H.w = f2bf_rn(f1.z) | ((unsigned)f2bf_rn(f1.w) << 16);
            size_t off = ((size_t)(b * 2 + rc2) * 16 + i) * 8192 + kc * 2048 + rowp * 8;
            *(uint4*)&Aprep[off] = H;
        }
    }
}

// ---------------- Kernel 1: question attention pooling ----------------
__global__ __launch_bounds__(256)
void qpool_kernel(const float* __restrict__ eq, const int* __restrict__ qlen,
                  const float* __restrict__ W_qa, float* __restrict__ q_state)
{
    int b = blockIdx.x;
    int t = threadIdx.x;
    int wave = t >> 6, lane = t & 63;
    __shared__ float att[LQ_];
    __shared__ float wsm[LQ_];
    const float* eqb = eq + (size_t)b * LQ_ * S_;

    for (int k = 0; k < 16; ++k) {
        int q = wave + 4 * k;
        const float* row = eqb + q * S_;
        float s = 0.f;
        #pragma unroll
        for (int j = 0; j < S_ / 64; ++j)
            s = fmaf(row[lane + 64 * j], W_qa[lane + 64 * j], s);
        #pragma unroll
        for (int off = 32; off >= 1; off >>= 1)
            s += __shfl_xor(s, off);
        if (lane == 0) att[q] = s;
    }
    __syncthreads();

    if (wave == 0) {
        int L = qlen[b];
        float v = att[lane] + ((lane < L) ? 0.f : NEGV);
        float m = v;
        #pragma unroll
        for (int off = 32; off >= 1; off >>= 1)
            m = fmaxf(m, __shfl_xor(m, off));
        float e = expf(v - m);
        float sum = e;
        #pragma unroll
        for (int off = 32; off >= 1; off >>= 1)
            sum += __shfl_xor(sum, off);
        wsm[lane] = e / sum;
    }
    __syncthreads();

    for (int d = t; d < S_; d += 256) {
        float acc = 0.f;
        #pragma unroll 8
        for (int q = 0; q < LQ_; ++q)
            acc = fmaf(wsm[q], eqb[q * S_ + d], acc);
        q_state[b * S_ + d] = acc;
    }
}

// ---------------- Kernel 2: q_start_inter / q_end_inter (f32 exact) --------
__global__ __launch_bounds__(512)
void inter_kernel(const float* __restrict__ q_state,
                  const float* __restrict__ W_qsi, const float* __restrict__ b_qsi,
                  const float* __restrict__ W_qei, const float* __restrict__ b_qei,
                  float* __restrict__ qsi, float* __restrict__ qei)
{
    int b = blockIdx.x;
    const float* W  = blockIdx.y ? W_qei : W_qsi;
    const float* bi = blockIdx.y ? b_qei : b_qsi;
    float*       o  = blockIdx.y ? qei   : qsi;
    int t = threadIdx.x, lane = t & 63, w = t >> 6;
    __shared__ float qs[S_];
    __shared__ float red[8][S_];
    qs[t] = q_state[b * S_ + t];
    __syncthreads();

    float z[8];
    #pragma unroll
    for (int k = 0; k < 8; ++k) z[k] = 0.f;
    const int d0 = w * 64;
    #pragma unroll 4
    for (int dd = 0; dd < 64; ++dd) {
        int d = d0 + dd;
        float q = qs[d];
        const float* row = W + (size_t)d * S_ + lane;
        #pragma unroll
        for (int k = 0; k < 8; ++k)
            z[k] = fmaf(q, row[k * 64], z[k]);
    }
    #pragma unroll
    for (int k = 0; k < 8; ++k) red[w][k * 64 + lane] = z[k];
    __syncthreads();
    float acc = bi[t];
    #pragma unroll
    for (int ww = 0; ww < 8; ++ww) acc += red[ww][t];
    o[b * S_ + t] = acc;
}

// ---------------- Kernel P: folded weight prep (bf16, full-width staged) ---
// Wc shorts: ((b*16)+i)*16384 + kc*4096 + col*8 + e ; k = i*32+kc*8+e.
template <int NT>
__global__ __launch_bounds__(512)
void prep_kernel(const float* __restrict__ W, const float* __restrict__ q_state,
                 const float* __restrict__ u_s, short* __restrict__ Wc)
{
    int bid = blockIdx.x;
    int i = bid >> 6, b = bid & 63;     // 64 consecutive blocks share W slice (L2)
    int col = threadIdx.x;
    __shared__ float scq[32], scu[32];
    if (col < 32) scq[col] = q_state[b * S_ + i * 32 + col];
    if (NT == 3 && col >= 32 && col < 64) scu[col - 32] = u_s[b * S_ + i * 32 + col - 32];
    __syncthreads();

    unsigned short h[32];
    #pragma unroll
    for (int d = 0; d < 32; ++d) {
        int D = i * 32 + d;
        float v;
        if (NT == 2)
            v = fmaf(scq[d], W[(size_t)D * S_ + col], W[(size_t)(S_ + D) * S_ + col]);
        else
            v = fmaf(scu[d], W[(size_t)D * S_ + col],
                fmaf(scq[d], W[(size_t)(S_ + D) * S_ + col], W[(size_t)(2 * S_ + D) * S_ + col]));
        h[d] = f2bf_rn(v);
    }
    size_t base = ((size_t)b * 16 + i) * 16384 + (size_t)col * 8;
    #pragma unroll
    for (int kc = 0; kc < 4; ++kc) {
        uint4 H;
        H.x = h[kc*8+0] | ((unsigned)h[kc*8+1] << 16);
        H.y = h[kc*8+2] | ((unsigned)h[kc*8+3] << 16);
        H.z = h[kc*8+4] | ((unsigned)h[kc*8+5] << 16);
        H.w = h[kc*8+6] | ((unsigned)h[kc*8+7] << 16);
        *(uint4*)&Wc[base + kc * 4096] = H;
    }
}

// ---------------- Kernel S: 128x512 full-width bf16 MFMA score -------------
// Complete rows per block -> masks applied here; no combine stage.
// Grid 256 = 4rc x 64b XCD-grouped. 8 waves = 2wr x 4wc; wave 64r x 128c.
template <bool END>
__global__ __launch_bounds__(512, 2)
void score_kernel(const short* __restrict__ Aprep, const short* __restrict__ Wc,
                  const float* __restrict__ inter, const float* __restrict__ Wsmall,
                  const int* __restrict__ slen, const int* __restrict__ sp,
                  float* __restrict__ out)
{
    const int t = threadIdx.x;
    const int lane = t & 63, wid = t >> 6;
    const int wr = wid >> 2, wc = wid & 3;
    const int l15 = lane & 15, l4 = lane >> 4;

    int lid = blockIdx.x;
    int xcd = lid & 7, slot = lid >> 3;        // slot 0..31
    int b  = xcd * 8 + (slot >> 2);
    int rc = slot & 3;                          // 128-row block index
    int rc2 = rc >> 1, hh = rc & 1;

    __shared__ __attribute__((aligned(16))) short As[2][4096];   // 16 KB
    __shared__ __attribute__((aligned(16))) short Bs[2][16384];  // 64 KB
    __shared__ float int_l[S_], wsm_l[S_];
    __shared__ float sm_red[128][4];

    int_l[t] = inter[b * S_ + t];
    wsm_l[t] = Wsmall[t];

    const char* Abase = (const char*)(Aprep + ((size_t)(b * 2 + rc2) * 16) * 8192);
    const char* Bbase = (const char*)(Wc    + ((size_t)b * 16) * 16384);

    f32x4 acc[4][8];
    #pragma unroll
    for (int r = 0; r < 4; ++r)
        #pragma unroll
        for (int c = 0; c < 8; ++c)
            acc[r][c] = (f32x4){0.f, 0.f, 0.f, 0.f};

    const int akc = t >> 7, ar = t & 127;   // A-stage thread map

    auto stage = [&](int i, int buf) {
        const char* ga = Abase + (size_t)i * 16384 + akc * 4096 + hh * 2048 + ar * 16;
        char* la = (char*)As[buf] + t * 16;
        __builtin_amdgcn_global_load_lds(
            (const __attribute__((address_space(1))) void*)ga,
            (__attribute__((address_space(3))) void*)la, 16, 0, 0);
        const char* gb = Bbase + (size_t)i * 32768 + t * 16;
        char* lb = (char*)Bs[buf] + t * 16;
        #pragma unroll
        for (int q = 0; q < 4; ++q)
            __builtin_amdgcn_global_load_lds(
                (const __attribute__((address_space(1))) void*)(gb + q * 8192),
                (__attribute__((address_space(3))) void*)(lb + q * 8192), 16, 0, 0);
    };

    stage(0, 0);

    for (int i = 0; i < 16; ++i) {
        const int buf = i & 1;
        if (i + 1 < 16) {
            stage(i + 1, buf ^ 1);
            asm volatile("s_waitcnt vmcnt(5)" ::: "memory");
        } else {
            asm volatile("s_waitcnt vmcnt(0)" ::: "memory");
        }
        __builtin_amdgcn_s_barrier();

        bf16x8 ah[4];
        #pragma unroll
        for (int r = 0; r < 4; ++r) {
            int rowp = wr * 64 + r * 16 + l15;           // < 128
            ah[r] = *(const bf16x8*)&As[buf][l4 * 1024 + rowp * 8];
        }
        #pragma unroll
        for (int c = 0; c < 8; ++c) {
            int col = wc * 128 + c * 16 + l15;           // < 512
            bf16x8 bh = *(const bf16x8*)&Bs[buf][l4 * 4096 + col * 8];
            #pragma unroll
            for (int r = 0; r < 4; ++r)
                acc[r][c] = __builtin_amdgcn_mfma_f32_16x16x32_bf16(ah[r], bh, acc[r][c], 0, 0, 0);
        }
        asm volatile("s_waitcnt lgkmcnt(0)" ::: "memory");
        __builtin_amdgcn_s_barrier();
    }

    // epilogue: + inter, relu, dot Wsmall, full-row reduce, masks, store
    #pragma unroll
    for (int r = 0; r < 4; ++r) {
        #pragma unroll
        for (int jj = 0; jj < 4; ++jj) {
            float pr = 0.f;
            #pragma unroll
            for (int c = 0; c < 8; ++c) {
                int col = wc * 128 + c * 16 + l15;
                float v = acc[r][c][jj] + int_l[col];
                v = fmaxf(v, 0.f);
                pr = fmaf(v, wsm_l[col], pr);
            }
            pr += __shfl_xor(pr, 1);
            pr += __shfl_xor(pr, 2);
            pr += __shfl_xor(pr, 4);
            pr += __shfl_xor(pr, 8);
            if (l15 == 0) sm_red[wr * 64 + r * 16 + l4 * 4 + jj][wc] = pr;
        }
    }
    __syncthreads();
    if (t < 128) {
        int l = rc * 128 + t;
        float s = sm_red[t][0] + sm_red[t][1] + sm_red[t][2] + sm_red[t][3];
        if (l >= slen[b]) s += NEGV;
        if (END) { if (l < sp[b]) s += NEGV; }
        out[b * LS_ + l] = s;
    }
}

// ---------------- candidate selection ----------------
__device__ inline int select_cands(const float* s_l, int t, int lane, int w,
                                   float* wred, int* wcnt, int* cand)
{
    float v = s_l[t];
    #pragma unroll
    for (int off = 32; off >= 1; off >>= 1)
        v = fmaxf(v, __shfl_xor(v, off));
    if (lane == 0) wred[w] = v;
    __syncthreads();
    float m = wred[0];
    #pragma unroll
    for (int k = 1; k < 8; ++k) m = fmaxf(m, wred[k]);
    float th = m - MARGIN;
    bool flag = s_l[t] >= th;
    unsigned long long bal = __ballot(flag);
    int rank = __popcll(bal & ((1ull << lane) - 1ull));
    if (lane == 0) wcnt[w] = (int)__popcll(bal);
    __syncthreads();
    int off = 0, total = 0;
    #pragma unroll
    for (int k = 0; k < 8; ++k) { if (k < w) off += wcnt[k]; total += wcnt[k]; }
    if (flag) { int pos = off + rank; if (pos < 8) cand[pos] = t; }
    __syncthreads();
    return total < 8 ? total : 8;
}

// ---------------- Kernel RF: fused rescue + finalize (one block per b) -----
// Exact f32 recompute of <=8 candidates, exact argmax, pred/sp/u_s.
template <bool END>
__global__ __launch_bounds__(512)
void rescue_fin_kernel(const float* __restrict__ support, const float* __restrict__ q_state,
                       const float* __restrict__ u_s_in, const float* __restrict__ Wbig,
                       const float* __restrict__ inter, const float* __restrict__ Wsmall,
                       const float* __restrict__ scores,
                       int* __restrict__ sp_ws, float* __restrict__ pred,
                       float* __restrict__ us_out)
{
    int b = blockIdx.x;
    int t = threadIdx.x, lane = t & 63, w = t >> 6;
    __shared__ float s_l[S_], qs_l[S_], us_l[S_], int_l[S_], wsm_l[S_];
    __shared__ float arow[8][S_];        // 16 KB
    __shared__ float red[8][4][S_];      // 64 KB
    __shared__ float wred[8];
    __shared__ int wcnt[8], cand[8];
    __shared__ float exact_v[8];
    __shared__ int best_sh;

    s_l[t]   = scores[b * S_ + t];
    qs_l[t]  = q_state[b * S_ + t];
    int_l[t] = inter[b * S_ + t];
    wsm_l[t] = Wsmall[t];
    if (END) us_l[t] = u_s_in[b * S_ + t];
    #pragma unroll
    for (int c = 0; c < 8; ++c) arow[c][t] = 0.f;
    __syncthreads();

    int cnt = select_cands(s_l, t, lane, w, wred, wcnt, cand);

    for (int c = 0; c < cnt; ++c)
        arow[c][t] = support[((size_t)(b * LS_ + cand[c])) * S_ + t];
    __syncthreads();

    const float* W1 = Wbig;
    const float* W2 = Wbig + (size_t)S_ * S_;
    const float* W3 = Wbig + (size_t)2 * S_ * S_;
    const int d0 = w * 64;

    for (int g = 0; g * 4 < cnt; ++g) {
        float z[4][8];
        #pragma unroll
        for (int cc = 0; cc < 4; ++cc)
            #pragma unroll
            for (int j = 0; j < 8; ++j) z[cc][j] = 0.f;

        #pragma unroll 2
        for (int dd = 0; dd < 64; ++dd) {
            int d = d0 + dd;
            float q = qs_l[d];
            float u = END ? us_l[d] : 0.f;
            float a[4], qa[4], ua[4];
            #pragma unroll
            for (int cc = 0; cc < 4; ++cc) {
                a[cc]  = arow[g * 4 + cc][d];
                qa[cc] = q * a[cc];
                if (END) ua[cc] = u * a[cc];
            }
            #pragma unroll
            for (int j = 0; j < 8; ++j) {
                int s = lane + 64 * j;
                float w1 = W1[(size_t)d * S_ + s];
                float w2 = W2[(size_t)d * S_ + s];
                if (END) {
                    float w3 = W3[(size_t)d * S_ + s];
                    #pragma unroll
                    for (int cc = 0; cc < 4; ++cc)
                        z[cc][j] = fmaf(ua[cc], w1, fmaf(qa[cc], w2, fmaf(a[cc], w3, z[cc][j])));
                } else {
                    #pragma unroll
                    for (int cc = 0; cc < 4; ++cc)
                        z[cc][j] = fmaf(qa[cc], w1, fmaf(a[cc], w2, z[cc][j]));
                }
            }
        }
        #pragma unroll
        for (int cc = 0; cc < 4; ++cc)
            #pragma unroll
            for (int j = 0; j < 8; ++j)
                red[w][cc][lane + 64 * j] = z[cc][j];
        __syncthreads();

        for (int cc = 0; cc < 4; ++cc) {
            float v = 0.f;
            #pragma unroll
            for (int ww = 0; ww < 8; ++ww) v += red[ww][cc][t];
            float p = fmaxf(v + int_l[t], 0.f) * wsm_l[t];
            #pragma unroll
            for (int off = 32; off >= 1; off >>= 1)
                p += __shfl_xor(p, off);
            if (lane == 0) wred[w] = p;
            __syncthreads();
            if (t == 0) {
                float e = ((wred[0] + wred[1]) + (wred[2] + wred[3])) +
                          ((wred[4] + wred[5]) + (wred[6] + wred[7]));
                exact_v[g * 4 + cc] = e;
            }
            __syncthreads();
        }
    }

    if (t == 0) {
        float bv = -INFINITY;
        int bi = cand[0];
        for (int c = 0; c < cnt; ++c) {
            float e = exact_v[c];
            if (e > bv) { bv = e; bi = cand[c]; }
        }
        best_sh = bi;
        pred[b] = (float)bi;
        if (!END) sp_ws[b] = bi;
    }
    __syncthreads();
    if (!END)
        us_out[b * S_ + t] = support[((size_t)(b * LS_ + best_sh)) * S_ + t];
}

// ---------------- launch ----------------
extern "C" void kernel_launch(void* const* d_in, const int* in_sizes, int n_in,
                              void* d_out, int out_size, void* d_ws, size_t ws_size,
                              hipStream_t stream)
{
    const float* eq    = (const float*)d_in[0];
    const float* es    = (const float*)d_in[1];
    const int*   qlen  = (const int*)d_in[2];
    const int*   slen  = (const int*)d_in[3];
    const float* W_qa  = (const float*)d_in[7];
    const float* W_qsi = (const float*)d_in[8];
    const float* b_qsi = (const float*)d_in[9];
    const float* W_qs  = (const float*)d_in[10];
    const float* W_ss  = (const float*)d_in[11];
    const float* W_qei = (const float*)d_in[12];
    const float* b_qei = (const float*)d_in[13];
    const float* W_qe  = (const float*)d_in[14];
    const float* W_es  = (const float*)d_in[15];

    float* out          = (float*)d_out;
    float* start_scores = out;
    float* end_scores   = out + B_ * LS_;
    float* pred_start   = out + 2 * B_ * LS_;
    float* pred_end     = out + 2 * B_ * LS_ + B_;

    float* ws      = (float*)d_ws;
    float* q_state = ws;                       // [B,S]
    float* qsi     = ws + B_ * S_;             // [B,S]
    float* qei     = ws + 2 * B_ * S_;         // [B,S]
    float* u_s     = ws + 3 * B_ * S_;         // [B,S]
    int*   sp_ws   = (int*)(ws + 4 * B_ * S_); // [B]
    short* Wc      = (short*)(ws + 4 * B_ * S_ + 64);   // 33.5 MB
    short* Aprep   = Wc + (size_t)B_ * 16 * 16384;      // 33.5 MB

    prep_support_kernel<<<512, 512, 0, stream>>>(es, Aprep);
    qpool_kernel<<<B_, 256, 0, stream>>>(eq, qlen, W_qa, q_state);
    inter_kernel<<<dim3(B_, 2), 512, 0, stream>>>(q_state, W_qsi, b_qsi, W_qei, b_qei, qsi, qei);

    // ---- start pass ----
    prep_kernel<2><<<1024, 512, 0, stream>>>(W_qs, q_state, nullptr, Wc);
    score_kernel<false><<<256, 512, 0, stream>>>(Aprep, Wc, qsi, W_ss, slen, nullptr, start_scores);
    rescue_fin_kernel<false><<<B_, 512, 0, stream>>>(es, q_state, nullptr, W_qs, qsi, W_ss,
                                                     start_scores, sp_ws, pred_start, u_s);

    // ---- end pass ----
    prep_kernel<3><<<1024, 512, 0, stream>>>(W_qe, q_state, u_s, Wc);
    score_kernel<true><<<256, 512, 0, stream>>>(Aprep, Wc, qei, W_es, slen, sp_ws, end_scores);
    rescue_fin_kernel<true><<<B_, 512, 0, stream>>>(es, q_state, u_s, W_qe, qei, W_es,
                                                    end_scores, nullptr, pred_end, nullptr);
}